// Round 14
// baseline (455.393 us; speedup 1.0000x reference)
//
#include <hip/hip_runtime.h>
#include <hip/hip_bf16.h>

typedef __hip_bfloat16 bf16;
typedef __attribute__((ext_vector_type(8))) short bf16x8;
typedef __attribute__((ext_vector_type(4))) float f32x4;

static __device__ __forceinline__ ushort f2bf(float f) {
    uint u = __float_as_uint(f);
    u += 0x7fff + ((u >> 16) & 1);   // RNE
    return (ushort)(u >> 16);
}

static __device__ __forceinline__ void gl_lds16(const void* g, void* l) {
    __builtin_amdgcn_global_load_lds(
        (const __attribute__((address_space(1))) uint*)g,
        (__attribute__((address_space(3))) uint*)l, 16, 0, 0);
}

// bijective XCD remap (m204): orig -> nid, any total count
static __device__ __forceinline__ int xcd_remap(int lid, int nwg) {
    int q = nwg >> 3, r = nwg & 7;
    int xcd = lid & 7, idx = lid >> 3;
    return (xcd < r ? xcd * (q + 1) : r * (q + 1) + (xcd - r) * q) + idx;
}

// featT geometry: padded pixel-major bf16, [yp(258)][xp(264)][64 ic slots]
// octet of ic-group g stored at slot g ^ G(xp), G(xp) = (xp ^ (xp>>2)) & 7.
// (G's bit2 = xp2^xp4 selects the 64B half; low bits spread banks for the
//  32-ic chunked reads -> 2-way LDS access, free per m136.)
#define FT_ROW 264
#define FT_IMG ((size_t)258 * 264 * 64)
// xn geometry: pixel-major bf16 [y(256)][x(256)][64 oc slots], octet ^ (x&7).
#define XN_IMG ((size_t)256 * 256 * 64)

// ---------------------------------------------------------------------------
// k_prep: w1 -> w_bf[c(2)][tap(9)][oc(64)][icl(32)] bf16, in-chunk swizzle
// slot4 = (icl>>3) ^ ((oc ^ (oc>>2)) & 3);  w2 -> w2_bf[tap][oc2][ic64];
// zero featT 1-px border (full records; swizzle-agnostic).
// ---------------------------------------------------------------------------
__global__ __launch_bounds__(256) void k_prep(const float* __restrict__ w1,
                                              const float* __restrict__ w2,
                                              ushort* __restrict__ w_bf,
                                              ushort* __restrict__ w2_bf,
                                              ushort* __restrict__ featT, int nb) {
    int i = blockIdx.x * 256 + threadIdx.x;
    if (i < 36864) {                       // w1: i = oc*576 + ic*9 + tap
        int oc = i / 576, rem = i - oc * 576;
        int ic = rem / 9, tap = rem - ic * 9;
        int c = ic >> 5, icl = ic & 31;
        int s4 = (icl >> 3) ^ ((oc ^ (oc >> 2)) & 3);
        w_bf[((c * 9 + tap) * 64 + oc) * 32 + s4 * 8 + (icl & 7)] = f2bf(w1[i]);
    } else if (i < 40064) {                // w2: j = (oc*64+ic)*25 + tap
        int j = i - 36864;
        int oc = j / 1600, rem = j - oc * 1600;
        int ic = rem / 25, tap = rem - ic * 25;
        w2_bf[(tap * 2 + oc) * 64 + ic] = f2bf(w2[j]);
    } else {                               // featT border zero
        int t = i - 40064;
        const int per = 1040 * 8;
        if (t >= nb * per) return;
        int b = t / per, u = t - b * per;
        int px = u >> 3, oct = u & 7;
        int yp, xp;
        if (px < 264)       { yp = 0;   xp = px; }
        else if (px < 528)  { yp = 257; xp = px - 264; }
        else { int k = px - 528; yp = 1 + (k >> 1); xp = (k & 1) ? 257 : 0; }
        ushort* p = featT + (size_t)b * FT_IMG + ((size_t)yp * FT_ROW + xp) * 64 + oct * 8;
        *(uint4*)p = make_uint4(0u, 0u, 0u, 0u);
    }
}

// ---------------------------------------------------------------------------
// k_tr: feat (nb,64,256,256) f32 -> featT bf16 pixel-major, G-swizzled.
// ---------------------------------------------------------------------------
__global__ __launch_bounds__(256) void k_tr(const float* __restrict__ feat_c,
                                            ushort* __restrict__ featT) {
    __shared__ ushort s_t[64][72];       // [ic][x], padded
    const int b = blockIdx.z, y = blockIdx.y, x0 = blockIdx.x * 64;
    const int t = threadIdx.x;
    const int xl = t & 63, icg = t >> 6;

    const float* fb = feat_c + (size_t)b * 64 * 65536 + (size_t)y * 256 + x0 + xl;
#pragma unroll
    for (int k = 0; k < 16; ++k) {
        int ic = icg * 16 + k;
        s_t[ic][xl] = f2bf(fb[(size_t)ic * 65536]);
    }
    __syncthreads();

    ushort* ob = featT + (size_t)b * FT_IMG + ((size_t)(y + 1) * FT_ROW + (x0 + 1)) * 64;
#pragma unroll
    for (int u2 = 0; u2 < 2; ++u2) {
        int u = u2 * 256 + t;            // 512 units: (x, octet)
        int x = u >> 3, oct = u & 7;
        int xx = x + 1;                  // local xp (x0 % 64 == 0)
        int g = (xx ^ (xx >> 2)) & 7;
        uint p0 = (uint)s_t[oct * 8 + 0][x] | ((uint)s_t[oct * 8 + 1][x] << 16);
        uint p1 = (uint)s_t[oct * 8 + 2][x] | ((uint)s_t[oct * 8 + 3][x] << 16);
        uint p2 = (uint)s_t[oct * 8 + 4][x] | ((uint)s_t[oct * 8 + 5][x] << 16);
        uint p3 = (uint)s_t[oct * 8 + 6][x] | ((uint)s_t[oct * 8 + 7][x] << 16);
        *(uint4*)(ob + (size_t)x * 64 + (oct ^ g) * 8) = make_uint4(p0, p1, p2, p3);
    }
}

// ---------------------------------------------------------------------------
// k_conv1 (MFMA, ic-CHUNKED): 3x3 conv + bias + BN + ReLU6 + L2-norm.
// ic split in two 32-ch chunks; LDS = 27.6K (s_in) + 12.3K (s_w) = 40.4 KB
// -> 4 blocks/CU (16 waves) for latency hiding. Same bytes/MFMAs as r13.
// ---------------------------------------------------------------------------
__global__ __launch_bounds__(256, 4) void k_conv1(
    const ushort* __restrict__ featT, const ushort* __restrict__ w_bf,
    const float* __restrict__ b1, const float* __restrict__ gamma,
    const float* __restrict__ beta, const float* __restrict__ rmean,
    const float* __restrict__ rvar, ushort* __restrict__ xn) {
    __shared__ __align__(16) ushort s_in[6 * 72 * 32];   // 27648 B
    __shared__ __align__(16) ushort s_w[6144];           // 12288 B
    __shared__ float2 s_bn[64];

    const int lid = blockIdx.x + (blockIdx.y << 2) + (blockIdx.z << 8);
    const int nid = xcd_remap(lid, (int)gridDim.z << 8);
    const int b   = nid >> 8;
    const int x0p = (nid & 3) * 64;
    const int y0  = ((nid >> 2) & 63) * 4;

    const int tid = threadIdx.x;
    const int lane = tid & 63;
    const int w    = tid >> 6;
    const int l15  = lane & 15;
    const int l4   = lane >> 4;

    if (tid < 64) {
        float inv = 1.0f / sqrtf(rvar[tid] + 1e-5f);
        float sA = inv * gamma[tid];
        float sB = (b1[tid] - rmean[tid]) * sA + beta[tid];
        s_bn[tid] = make_float2(sA, sB);
    }

    const ushort* fT = featT + (size_t)b * FT_IMG;

    f32x4 acc[4][4];
#pragma unroll
    for (int m = 0; m < 4; m++)
#pragma unroll
        for (int n = 0; n < 4; n++) acc[m][n] = (f32x4){0.f, 0.f, 0.f, 0.f};

    for (int c = 0; c < 2; ++c) {
        if (c) __syncthreads();          // all chunk-0 LDS reads done
        // ---- stage A chunk c: 6 rows x 72 px x 32 ic = 30 issues (8,8,7,7).
        // per row: 4 full 16-px issues + overlapped tail (px 56..71; the
        // px56-63 rewrite carries identical bytes -> benign).
        {
            int st  = (w < 2) ? w * 8 : 16 + (w - 2) * 7;
            int cnt = (w < 2) ? 8 : 7;
            for (int q = 0; q < cnt; ++q) {
                int i = st + q;
                int r = i / 5, o = i - r * 5;
                int px0 = (o < 4) ? o * 16 : 56;
                int px = px0 + (lane >> 2);
                int h = c ^ (((px >> 2) ^ (px >> 4)) & 1);   // G(xp)>>2
                const ushort* g = fT + ((size_t)(y0 + r) * FT_ROW + x0p + px) * 64 +
                                  h * 32 + (lane & 3) * 8;
                gl_lds16(g, (char*)s_in + r * 4608 + px0 * 64);
            }
        }
        for (int dy = 0; dy < 3; ++dy) {
            __syncthreads();             // prev dy's s_w reads done
            for (int q = 0; q < 3; ++q) {    // stage w(c,dy): 12288 B
                int j = w * 3 + q;
                const ushort* g = w_bf + (c * 9 + dy * 3) * 2048 + j * 512 + lane * 8;
                gl_lds16(g, (char*)s_w + j * 1024);
            }
            __syncthreads();             // s_w (and A on first dy) resident
#pragma unroll
            for (int dx = 0; dx < 3; dx++) {
                bf16x8 a[4], bb[4];
#pragma unroll
                for (int m = 0; m < 4; m++) {
                    int col = m * 16 + l15 + dx;
                    int s4 = l4 ^ ((col ^ (col >> 2)) & 3);
                    a[m] = *(const bf16x8*)&s_in[((w + dy) * 72 + col) * 32 + s4 * 8];
                }
#pragma unroll
                for (int n = 0; n < 4; n++) {
                    int oc = n * 16 + l15;
                    int s4 = l4 ^ ((oc ^ (oc >> 2)) & 3);
                    bb[n] = *(const bf16x8*)&s_w[(dx * 64 + oc) * 32 + s4 * 8];
                }
#pragma unroll
                for (int m = 0; m < 4; m++)
#pragma unroll
                    for (int n = 0; n < 4; n++)   // C[oc row, px col]
                        acc[m][n] = __builtin_amdgcn_mfma_f32_16x16x32_bf16(
                            bb[n], a[m], acc[m][n], 0, 0, 0);
            }
        }
    }

    float sA[4][4], sB[4][4];
#pragma unroll
    for (int n = 0; n < 4; n++)
#pragma unroll
        for (int j = 0; j < 4; j++) {
            float2 t = s_bn[n * 16 + l4 * 4 + j];
            sA[n][j] = t.x; sB[n][j] = t.y;
        }
    const int y = y0 + w;
    ushort* xb = xn + (size_t)b * XN_IMG;

#pragma unroll
    for (int m = 0; m < 4; m++) {
        float vv[4][4];
        float ss = 0.f;
#pragma unroll
        for (int n = 0; n < 4; n++)
#pragma unroll
            for (int j = 0; j < 4; j++) {
                float v = fmaf(acc[m][n][j], sA[n][j], sB[n][j]);
                v = fminf(fmaxf(v, 0.f), 6.f);
                vv[n][j] = v;
                ss = fmaf(v, v, ss);
            }
        ss += __shfl_xor(ss, 16);
        ss += __shfl_xor(ss, 32);
        float nrm = sqrtf(ss);
        float sc = (nrm > 0.09f) ? (1.0f / (nrm + 9e-8f)) : 0.f;

        int x = x0p + m * 16 + l15;
        ushort* pb = xb + ((size_t)y * 256 + x) * 64;
        int so = (l4 & 1) * 4;
#pragma unroll
        for (int n = 0; n < 4; n++) {
            int oct = n * 2 + (l4 >> 1);
            int slot = oct ^ (x & 7);
            uint2 pk;
            pk.x = (uint)f2bf(vv[n][0] * sc) | ((uint)f2bf(vv[n][1] * sc) << 16);
            pk.y = (uint)f2bf(vv[n][2] * sc) | ((uint)f2bf(vv[n][3] * sc) << 16);
            *(uint2*)(pb + slot * 8 + so) = pk;
        }
    }
}

// ---------------------------------------------------------------------------
// k_conv2 (MFMA, ROW-SAMPLED): 5x5 conv + sigmoid at the 130 sampled rows.
// ---------------------------------------------------------------------------
__global__ __launch_bounds__(256, 2) void k_conv2(
    const ushort* __restrict__ xn, const ushort* __restrict__ w2_bf,
    const float* __restrict__ b2, float* __restrict__ dmap_raw2) {
    __shared__ __align__(16) ushort s_in[11 * 80 * 32];   // 56320 B

    // grid (4, 33, nb), XCD-swizzled
    const int lid = blockIdx.x + (blockIdx.y << 2) + blockIdx.z * 132;
    const int nid = xcd_remap(lid, (int)gridDim.z * 132);
    const int b   = nid / 132;
    const int rem = nid - b * 132;
    const int x0  = (rem & 3) * 64;
    const int oy0 = (rem >> 2) * 4;

    const int tid = threadIdx.x;
    const int lane = tid & 63;
    const int w    = tid >> 6;
    const int l15  = lane & 15;
    const int l4   = lane >> 4;

    const float SC = (float)(252.0 / 130.0);
    const int syb = (int)floorf((float)oy0 * SC);
    const int oy  = oy0 + w;
    const int syrel = (int)floorf((float)oy * SC) - syb;   // 0..6

    const ushort* xb = xn + (size_t)b * XN_IMG;

    f32x4 acc[4];
#pragma unroll
    for (int n = 0; n < 4; n++) acc[n] = (f32x4){0.f, 0.f, 0.f, 0.f};

    for (int c = 0; c < 2; ++c) {
        if (c) __syncthreads();            // chunk-0 reads complete
        {
            int st  = (w < 3) ? w * 14 : 42;
            int cnt = (w < 3) ? 14 : 13;
            for (int q = 0; q < cnt; ++q) {
                int i = st + q;
                int r = i / 5;
                int px0 = (i - r * 5) * 16;
                int gr = min(syb + r, 255);
                int px = px0 + (lane >> 2);
                int gx = x0 + px;
                const ushort* g = xb + (size_t)(gr * 256 + gx) * 64 +
                                  ((((gx >> 2) & 1) ^ c) * 32) + (lane & 3) * 8;
                gl_lds16(g, (char*)s_in + i * 1024);
            }
        }
        __syncthreads();

#pragma unroll
        for (int dy = 0; dy < 5; dy++) {
#pragma unroll
            for (int dx = 0; dx < 5; dx++) {
                bf16x8 aw;
                if (l15 < 2)
                    aw = *(const bf16x8*)(w2_bf + ((dy * 5 + dx) * 2 + l15) * 64 +
                                          c * 32 + l4 * 8);
                else
                    aw = (bf16x8){0, 0, 0, 0, 0, 0, 0, 0};
                bf16x8 bx[4];
#pragma unroll
                for (int n = 0; n < 4; n++) {
                    int px = n * 16 + l15 + dx;
                    int slot4 = l4 ^ (px & 3);
                    bx[n] = *(const bf16x8*)&s_in[((syrel + dy) * 80 + px) * 32 + slot4 * 8];
                }
#pragma unroll
                for (int n = 0; n < 4; n++)
                    acc[n] = __builtin_amdgcn_mfma_f32_16x16x32_bf16(
                        aw, bx[n], acc[n], 0, 0, 0);
            }
        }
    }

    if (l4 == 0 && oy < 130) {
        float bias0 = b2[0], bias1 = b2[1];
#pragma unroll
        for (int n = 0; n < 4; n++) {
            int ox = x0 + n * 16 + l15;
            if (ox < 252) {
                float v0 = acc[n][0] + bias0;
                float v1 = acc[n][1] + bias1;
                size_t o = (size_t)b * 65520 + (size_t)oy * 252 + ox;
                dmap_raw2[o] = 1.f / (1.f + expf(-v0));
                dmap_raw2[o + 32760] = 1.f / (1.f + expf(-v1));
            }
        }
    }
}

// ---------------------------------------------------------------------------
// k_dmap: fused nearest(cols)+mask -> bilinear 130->128 -> bilinear 128->130
// -> out_dmap + normalize/cumsum -> grid. ch0=h->y(grid+1), ch1=w->x(grid+0).
// ---------------------------------------------------------------------------
__global__ __launch_bounds__(256) void k_dmap(const float* __restrict__ dmap_raw2,
                                              float* __restrict__ out_dmap,
                                              float* __restrict__ grid) {
    __shared__ float sA[16900];   // 130x130
    __shared__ float sB[16384];   // 128x128
    const int ch = blockIdx.x, b = blockIdx.y;
    const int tid = threadIdx.x;
    const float SC = (float)(252.0 / 130.0);

    const float* src = dmap_raw2 + (size_t)b * 65520 + (size_t)ch * 32760;
    for (int i = tid; i < 16900; i += 256) {
        int oy = i / 130, ox = i - oy * 130;
        int sx = (int)floorf((float)ox * SC);
        float m = (oy >= 1 && oy <= 128 && ox >= 1 && ox <= 128) ? 2.0f : 0.0f;
        sA[i] = src[oy * 252 + sx] + 0.0009f + m;
    }
    __syncthreads();

    {   // bilinear 130 -> 128
        const float sc = (float)(130.0 / 128.0);
        for (int i = tid; i < 16384; i += 256) {
            int oy = i >> 7, ox = i & 127;
            float sy = ((float)oy + 0.5f) * sc - 0.5f;
            float sx = ((float)ox + 0.5f) * sc - 0.5f;
            float y0f = floorf(sy), x0f = floorf(sx);
            float wy = sy - y0f, wx = sx - x0f;
            int y0 = max(min((int)y0f, 129), 0), y1 = max(min((int)y0f + 1, 129), 0);
            int x0 = max(min((int)x0f, 129), 0), x1 = max(min((int)x0f + 1, 129), 0);
            float top = sA[y0 * 130 + x0] * (1.f - wx) + sA[y0 * 130 + x1] * wx;
            float bot = sA[y1 * 130 + x0] * (1.f - wx) + sA[y1 * 130 + x1] * wx;
            sB[i] = top * (1.f - wy) + bot * wy;
        }
    }
    __syncthreads();

    {   // bilinear 128 -> 130, write out_dmap, stash in sA
        const float sc = (float)(128.0 / 130.0);
        float* od = out_dmap + ((size_t)b * 2 + ch) * 16900;
        for (int i = tid; i < 16900; i += 256) {
            int oy = i / 130, ox = i - oy * 130;
            float sy = ((float)oy + 0.5f) * sc - 0.5f;
            float sx = ((float)ox + 0.5f) * sc - 0.5f;
            float y0f = floorf(sy), x0f = floorf(sx);
            float wy = sy - y0f, wx = sx - x0f;
            int y0 = max(min((int)y0f, 127), 0), y1 = max(min((int)y0f + 1, 127), 0);
            int x0 = max(min((int)x0f, 127), 0), x1 = max(min((int)x0f + 1, 127), 0);
            float top = sB[y0 * 128 + x0] * (1.f - wx) + sB[y0 * 128 + x1] * wx;
            float bot = sB[y1 * 128 + x0] * (1.f - wx) + sB[y1 * 128 + x1] * wx;
            float v = top * (1.f - wy) + bot * wy;
            od[i] = v;
            sA[i] = v;
        }
    }
    __syncthreads();

    if (tid < 130) {
        float* g = grid + (size_t)b * 32768;
        if (ch == 0) {          // ch0 = h -> cumsum down rows -> y (grid+1)
            float s = 0.f;
            for (int r = 0; r < 130; r++) s += sA[r * 130 + tid];
            float inv = 1.f / s;
            float cs = 0.f;
            for (int r = 0; r < 130; r++) {
                cs += sA[r * 130 + tid] * inv;
                if (r >= 1 && r <= 128 && tid >= 1 && tid <= 128)
                    g[((r - 1) * 128 + (tid - 1)) * 2 + 1] = cs * 2.f - 1.f;
            }
        } else {                // ch1 = w -> cumsum across cols -> x (grid+0)
            const float* row = sA + tid * 130;
            float s = 0.f;
            for (int x = 0; x < 130; x++) s += row[x];
            float inv = 1.f / s;
            float cs = 0.f;
            for (int x = 0; x < 130; x++) {
                cs += row[x] * inv;
                if (x >= 1 && x <= 128 && tid >= 1 && tid <= 128)
                    g[((tid - 1) * 128 + (x - 1)) * 2 + 0] = cs * 2.f - 1.f;
            }
        }
    }
}

// ---------------------------------------------------------------------------
// k_sample: grid_sample_bilinear(feat, grid) -> dst (nb,64,128,128) f32.
// ---------------------------------------------------------------------------
__global__ __launch_bounds__(256) void k_sample(const float* __restrict__ feat_c,
                                                const float* __restrict__ grid,
                                                float* __restrict__ dst_c) {
    const int lid = blockIdx.x + (blockIdx.y << 3) + (blockIdx.z << 6);
    const int nid = xcd_remap(lid, (int)gridDim.z << 6);
    const int b = nid >> 6;
    const int x = ((nid & 7) << 4) + (threadIdx.x & 15);
    const int y = (((nid >> 3) & 7) << 4) + (threadIdx.x >> 4);

    const float* g = grid + (((size_t)b * 128 + y) * 128 + x) * 2;
    float gx = g[0], gy = g[1];
    float ix = (gx + 1.f) * 128.f - 0.5f;
    float iy = (gy + 1.f) * 128.f - 0.5f;
    float x0f = floorf(ix), y0f = floorf(iy);
    float wx = ix - x0f, wy = iy - y0f;
    int ix0 = (int)x0f, iy0 = (int)y0f;
    int ix1 = ix0 + 1, iy1 = iy0 + 1;
    float vx0 = ((unsigned)ix0 < 256u) ? 1.f : 0.f;
    float vx1 = ((unsigned)ix1 < 256u) ? 1.f : 0.f;
    float vy0 = ((unsigned)iy0 < 256u) ? 1.f : 0.f;
    float vy1 = ((unsigned)iy1 < 256u) ? 1.f : 0.f;
    int cx0 = max(min(ix0, 255), 0), cx1 = max(min(ix1, 255), 0);
    int cy0 = max(min(iy0, 255), 0), cy1 = max(min(iy1, 255), 0);
    float w00 = (1.f - wx) * (1.f - wy) * vx0 * vy0;
    float w01 = wx * (1.f - wy) * vx1 * vy0;
    float w10 = (1.f - wx) * wy * vx0 * vy1;
    float w11 = wx * wy * vx1 * vy1;

    const float* fb = feat_c + (size_t)b * 64 * 65536;
    int o00 = cy0 * 256 + cx0, o01 = cy0 * 256 + cx1;
    int o10 = cy1 * 256 + cx0, o11 = cy1 * 256 + cx1;
    float* d = dst_c + (size_t)b * 64 * 16384 + (size_t)y * 128 + x;
#pragma unroll 4
    for (int c = 0; c < 64; c++) {
        const float* fc = fb + (size_t)c * 65536;
        d[(size_t)c * 16384] = fc[o00] * w00 + fc[o01] * w01 +
                               fc[o10] * w10 + fc[o11] * w11;
    }
}

// ---------------------------------------------------------------------------
static inline size_t align256(size_t x) { return (x + 255) & ~(size_t)255; }

extern "C" void kernel_launch(void* const* d_in, const int* in_sizes, int n_in,
                              void* d_out, int out_size, void* d_ws, size_t ws_size,
                              hipStream_t stream) {
    const float* feat  = (const float*)d_in[0];
    const float* w1    = (const float*)d_in[1];
    const float* b1    = (const float*)d_in[2];
    const float* gamma = (const float*)d_in[3];
    const float* beta  = (const float*)d_in[4];
    const float* rmean = (const float*)d_in[5];
    const float* rvar  = (const float*)d_in[6];
    const float* w2    = (const float*)d_in[7];
    const float* b2    = (const float*)d_in[8];

    float* out = (float*)d_out;                 // reference outputs are f32
    float* out_dst  = out;                      // (16,64,128,128)
    float* out_dmap = out + 16777216;           // (16,2,130,130)

    // pick images-per-chunk nb adaptively from ws_size (deterministic)
    int nb = 1;
    const int cands[5] = {16, 8, 4, 2, 1};
    for (int k = 0; k < 5; ++k) {
        int n = cands[k];
        size_t need = align256((size_t)n * FT_IMG * 2)     // featT bf16 padded
                    + align256((size_t)n * XN_IMG * 2)     // xn bf16 pixel-major
                    + align256(73728)                      // w_bf
                    + align256(12800)                      // w2_bf
                    + align256((size_t)n * 65520 * 4)      // dmap_raw2
                    + align256((size_t)n * 131072);        // grid
        if (need <= ws_size) { nb = n; break; }
    }

    char* p = (char*)d_ws;
    ushort* featT    = (ushort*)p; p += align256((size_t)nb * FT_IMG * 2);
    ushort* xn       = (ushort*)p; p += align256((size_t)nb * XN_IMG * 2);
    ushort* w_bf     = (ushort*)p; p += align256(73728);
    ushort* w2_bf    = (ushort*)p; p += align256(12800);
    float* dmap_raw2 = (float*)p;  p += align256((size_t)nb * 65520 * 4);
    float* grid      = (float*)p;

    k_prep<<<(40064 + nb * 8320 + 255) / 256, 256, 0, stream>>>(
        w1, w2, w_bf, w2_bf, featT, nb);

    const int nchunks = 16 / nb;
    for (int c = 0; c < nchunks; ++c) {
        const float* feat_c = feat + (size_t)c * nb * 64 * 65536;
        float* dst_c  = out_dst  + (size_t)c * nb * 64 * 16384;
        float* dmap_c = out_dmap + (size_t)c * nb * 2 * 16900;

        k_tr<<<dim3(4, 256, nb), 256, 0, stream>>>(feat_c, featT);
        k_conv1<<<dim3(4, 64, nb), 256, 0, stream>>>(featT, w_bf, b1, gamma,
                                                     beta, rmean, rvar, xn);
        k_conv2<<<dim3(4, 33, nb), 256, 0, stream>>>(xn, w2_bf, b2, dmap_raw2);
        k_dmap<<<dim3(2, nb), 256, 0, stream>>>(dmap_raw2, dmap_c, grid);
        k_sample<<<dim3(8, 8, nb), 256, 0, stream>>>(feat_c, grid, dst_c);
    }
}

// Round 16
// 399.150 us; speedup vs baseline: 1.1409x; 1.1409x over previous
//
#include <hip/hip_runtime.h>
#include <hip/hip_bf16.h>

typedef __hip_bfloat16 bf16;
typedef __attribute__((ext_vector_type(8))) short bf16x8;
typedef __attribute__((ext_vector_type(4))) float f32x4;

static __device__ __forceinline__ ushort f2bf(float f) {
    uint u = __float_as_uint(f);
    u += 0x7fff + ((u >> 16) & 1);   // RNE
    return (ushort)(u >> 16);
}

static __device__ __forceinline__ void gl_lds16(const void* g, void* l) {
    __builtin_amdgcn_global_load_lds(
        (const __attribute__((address_space(1))) uint*)g,
        (__attribute__((address_space(3))) uint*)l, 16, 0, 0);
}

// bijective XCD remap (m204): orig -> nid, any total count
static __device__ __forceinline__ int xcd_remap(int lid, int nwg) {
    int q = nwg >> 3, r = nwg & 7;
    int xcd = lid & 7, idx = lid >> 3;
    return (xcd < r ? xcd * (q + 1) : r * (q + 1) + (xcd - r) * q) + idx;
}

// featT geometry: padded pixel-major bf16, [yp(258)][xp(264)][64 ic slots]
// value of (y,x,ic) at yp=y+1, xp=x+1, octet slot (ic>>3) ^ (xp&7), elem ic&7.
#define FT_ROW 264
#define FT_IMG ((size_t)258 * 264 * 64)
// xn geometry: pixel-major bf16 [y(256)][x(256)][64 oc slots], octet ^ (x&7).
#define XN_IMG ((size_t)256 * 256 * 64)

// ---------------------------------------------------------------------------
// k_prep: w1 -> w_bf[tap][oc][ic ^ ((oc&7)<<3)] bf16 (SWIZZLED, for LDS-staged
// conv1); w2 -> w2_bf[tap(25)][oc(2)][ic(64)]; zero featT 1-px border.
// ---------------------------------------------------------------------------
__global__ __launch_bounds__(256) void k_prep(const float* __restrict__ w1,
                                              const float* __restrict__ w2,
                                              ushort* __restrict__ w_bf,
                                              ushort* __restrict__ w2_bf,
                                              ushort* __restrict__ featT, int nb) {
    int i = blockIdx.x * 256 + threadIdx.x;
    if (i < 36864) {                       // w1: i = ((oc*64+ic)*3+dy)*3+dx
        int oc = i / 576, rem = i - oc * 576;
        int ic = rem / 9, tap = rem - ic * 9;
        w_bf[tap * 4096 + oc * 64 + (ic ^ ((oc & 7) << 3))] = f2bf(w1[i]);
    } else if (i < 40064) {                // w2: j = (oc*64+ic)*25 + tap
        int j = i - 36864;
        int oc = j / 1600, rem = j - oc * 1600;
        int ic = rem / 25, tap = rem - ic * 25;
        w2_bf[(tap * 2 + oc) * 64 + ic] = f2bf(w2[j]);
    } else {                               // featT border zero
        int t = i - 40064;
        const int per = 1040 * 8;
        if (t >= nb * per) return;
        int b = t / per, u = t - b * per;
        int px = u >> 3, oct = u & 7;
        int yp, xp;
        if (px < 264)       { yp = 0;   xp = px; }
        else if (px < 528)  { yp = 257; xp = px - 264; }
        else { int k = px - 528; yp = 1 + (k >> 1); xp = (k & 1) ? 257 : 0; }
        ushort* p = featT + (size_t)b * FT_IMG + ((size_t)yp * FT_ROW + xp) * 64 + oct * 8;
        *(uint4*)p = make_uint4(0u, 0u, 0u, 0u);
    }
}

// ---------------------------------------------------------------------------
// k_tr: feat (nb,64,256,256) f32 -> featT bf16 pixel-major, swizzled.
// ---------------------------------------------------------------------------
__global__ __launch_bounds__(256) void k_tr(const float* __restrict__ feat_c,
                                            ushort* __restrict__ featT) {
    __shared__ ushort s_t[64][72];       // [ic][x], padded
    const int b = blockIdx.z, y = blockIdx.y, x0 = blockIdx.x * 64;
    const int t = threadIdx.x;
    const int xl = t & 63, icg = t >> 6;

    const float* fb = feat_c + (size_t)b * 64 * 65536 + (size_t)y * 256 + x0 + xl;
#pragma unroll
    for (int k = 0; k < 16; ++k) {
        int ic = icg * 16 + k;
        s_t[ic][xl] = f2bf(fb[(size_t)ic * 65536]);
    }
    __syncthreads();

    ushort* ob = featT + (size_t)b * FT_IMG + ((size_t)(y + 1) * FT_ROW + (x0 + 1)) * 64;
#pragma unroll
    for (int u2 = 0; u2 < 2; ++u2) {
        int u = u2 * 256 + t;            // 512 units: (x, octet)
        int x = u >> 3, oct = u & 7;
        int xp7 = (x + 1) & 7;           // (xp&7), since x0 % 64 == 0
        uint p0 = (uint)s_t[oct * 8 + 0][x] | ((uint)s_t[oct * 8 + 1][x] << 16);
        uint p1 = (uint)s_t[oct * 8 + 2][x] | ((uint)s_t[oct * 8 + 3][x] << 16);
        uint p2 = (uint)s_t[oct * 8 + 4][x] | ((uint)s_t[oct * 8 + 5][x] << 16);
        uint p3 = (uint)s_t[oct * 8 + 6][x] | ((uint)s_t[oct * 8 + 7][x] << 16);
        *(uint4*)(ob + (size_t)x * 64 + (oct ^ xp7) * 8) = make_uint4(p0, p1, p2, p3);
    }
}

// ---------------------------------------------------------------------------
// k_conv1 (MFMA + DMA staging, known-good r13 form): 3x3 conv + bias + BN +
// ReLU6 + L2-norm. LDS-staged weights (per-dy), 2 blocks/CU, 7 barriers.
// ---------------------------------------------------------------------------
__global__ __launch_bounds__(256, 2) void k_conv1(
    const ushort* __restrict__ featT, const ushort* __restrict__ w_bf,
    const float* __restrict__ b1, const float* __restrict__ gamma,
    const float* __restrict__ beta, const float* __restrict__ rmean,
    const float* __restrict__ rvar, ushort* __restrict__ xn) {
    __shared__ __align__(16) ushort s_in[6 * 72 * 64];   // 55296 B
    __shared__ __align__(16) ushort s_w[12288];          // 24576 B
    __shared__ float2 s_bn[64];

    const int lid = blockIdx.x + (blockIdx.y << 2) + (blockIdx.z << 8);
    const int nid = xcd_remap(lid, (int)gridDim.z << 8);
    const int b   = nid >> 8;
    const int x0p = (nid & 3) * 64;
    const int y0  = ((nid >> 2) & 63) * 4;

    const int tid = threadIdx.x;
    const int lane = tid & 63;
    const int w    = tid >> 6;
    const int l15  = lane & 15;
    const int l4   = lane >> 4;

    if (tid < 64) {
        float inv = 1.0f / sqrtf(rvar[tid] + 1e-5f);
        float sA = inv * gamma[tid];
        float sB = (b1[tid] - rmean[tid]) * sA + beta[tid];
        s_bn[tid] = make_float2(sA, sB);
    }

    const ushort* fT = featT + (size_t)b * FT_IMG;
    {
        int aStart = w * 13 + (w < 2 ? w : 2);       // {0,14,28,41}
        int aCnt   = (w < 2) ? 14 : 13;
        for (int q = 0; q < aCnt; ++q) {
            int o = (aStart + q) * 1024;
            int r = o / 9216;
            int rem = o - r * 9216;
            const ushort* g = fT + ((size_t)(y0 + r) * FT_ROW + x0p) * 64 +
                              (rem >> 1) + lane * 8;
            gl_lds16(g, (char*)s_in + o);
        }
    }

    f32x4 acc[4][4];
#pragma unroll
    for (int m = 0; m < 4; m++)
#pragma unroll
        for (int n = 0; n < 4; n++) acc[m][n] = (f32x4){0.f, 0.f, 0.f, 0.f};

    for (int dy = 0; dy < 3; dy++) {
        __syncthreads();
        {
            for (int q = 0; q < 6; ++q) {
                int o = (w * 6 + q) * 1024;
                const ushort* g = w_bf + dy * 12288 + (o >> 1) + lane * 8;
                gl_lds16(g, (char*)s_w + o);
            }
        }
        __syncthreads();
#pragma unroll
        for (int dx = 0; dx < 3; dx++) {
#pragma unroll
            for (int ks = 0; ks < 2; ks++) {
                bf16x8 a[4], bb[4];
#pragma unroll
                for (int m = 0; m < 4; m++) {
                    int c = m * 16 + l15 + dx;
                    int slot = (ks * 4 + l4) ^ (c & 7);
                    a[m] = *(const bf16x8*)&s_in[((w + dy) * 72 + c) * 64 + slot * 8];
                }
#pragma unroll
                for (int n = 0; n < 4; n++) {
                    int oc = n * 16 + l15;
                    int slot = (ks * 4 + l4) ^ (oc & 7);
                    bb[n] = *(const bf16x8*)&s_w[(dx * 64 + oc) * 64 + slot * 8];
                }
#pragma unroll
                for (int m = 0; m < 4; m++)
#pragma unroll
                    for (int n = 0; n < 4; n++)   // C[oc row, px col]
                        acc[m][n] = __builtin_amdgcn_mfma_f32_16x16x32_bf16(
                            bb[n], a[m], acc[m][n], 0, 0, 0);
            }
        }
    }

    float sA[4][4], sB[4][4];
#pragma unroll
    for (int n = 0; n < 4; n++)
#pragma unroll
        for (int j = 0; j < 4; j++) {
            float2 t = s_bn[n * 16 + l4 * 4 + j];
            sA[n][j] = t.x; sB[n][j] = t.y;
        }
    const int y = y0 + w;
    ushort* xb = xn + (size_t)b * XN_IMG;

#pragma unroll
    for (int m = 0; m < 4; m++) {
        float vv[4][4];
        float ss = 0.f;
#pragma unroll
        for (int n = 0; n < 4; n++)
#pragma unroll
            for (int j = 0; j < 4; j++) {
                float v = fmaf(acc[m][n][j], sA[n][j], sB[n][j]);
                v = fminf(fmaxf(v, 0.f), 6.f);
                vv[n][j] = v;
                ss = fmaf(v, v, ss);
            }
        ss += __shfl_xor(ss, 16);
        ss += __shfl_xor(ss, 32);
        float nrm = sqrtf(ss);
        float sc = (nrm > 0.09f) ? (1.0f / (nrm + 9e-8f)) : 0.f;

        int x = x0p + m * 16 + l15;
        ushort* pb = xb + ((size_t)y * 256 + x) * 64;
        int so = (l4 & 1) * 4;
#pragma unroll
        for (int n = 0; n < 4; n++) {
            int oct = n * 2 + (l4 >> 1);
            int slot = oct ^ (x & 7);
            uint2 pk;
            pk.x = (uint)f2bf(vv[n][0] * sc) | ((uint)f2bf(vv[n][1] * sc) << 16);
            pk.y = (uint)f2bf(vv[n][2] * sc) | ((uint)f2bf(vv[n][3] * sc) << 16);
            *(uint2*)(pb + slot * 8 + so) = pk;
        }
    }
}

// ---------------------------------------------------------------------------
// k_conv2 (MFMA, ROW-SAMPLED): 5x5 conv + sigmoid at the 130 sampled rows.
// ---------------------------------------------------------------------------
__global__ __launch_bounds__(256, 2) void k_conv2(
    const ushort* __restrict__ xn, const ushort* __restrict__ w2_bf,
    const float* __restrict__ b2, float* __restrict__ dmap_raw2) {
    __shared__ __align__(16) ushort s_in[11 * 80 * 32];   // 56320 B

    // grid (4, 33, nb), XCD-swizzled
    const int lid = blockIdx.x + (blockIdx.y << 2) + blockIdx.z * 132;
    const int nid = xcd_remap(lid, (int)gridDim.z * 132);
    const int b   = nid / 132;
    const int rem = nid - b * 132;
    const int x0  = (rem & 3) * 64;
    const int oy0 = (rem >> 2) * 4;

    const int tid = threadIdx.x;
    const int lane = tid & 63;
    const int w    = tid >> 6;
    const int l15  = lane & 15;
    const int l4   = lane >> 4;

    const float SC = (float)(252.0 / 130.0);
    const int syb = (int)floorf((float)oy0 * SC);
    const int oy  = oy0 + w;
    const int syrel = (int)floorf((float)oy * SC) - syb;   // 0..6

    const ushort* xb = xn + (size_t)b * XN_IMG;

    f32x4 acc[4];
#pragma unroll
    for (int n = 0; n < 4; n++) acc[n] = (f32x4){0.f, 0.f, 0.f, 0.f};

    for (int c = 0; c < 2; ++c) {
        if (c) __syncthreads();            // chunk-0 reads complete
        {
            int st  = (w < 3) ? w * 14 : 42;
            int cnt = (w < 3) ? 14 : 13;
            for (int q = 0; q < cnt; ++q) {
                int i = st + q;
                int r = i / 5;
                int px0 = (i - r * 5) * 16;
                int gr = min(syb + r, 255);
                int px = px0 + (lane >> 2);
                int gx = x0 + px;
                const ushort* g = xb + (size_t)(gr * 256 + gx) * 64 +
                                  ((((gx >> 2) & 1) ^ c) * 32) + (lane & 3) * 8;
                gl_lds16(g, (char*)s_in + i * 1024);
            }
        }
        __syncthreads();

#pragma unroll
        for (int dy = 0; dy < 5; dy++) {
#pragma unroll
            for (int dx = 0; dx < 5; dx++) {
                bf16x8 aw;
                if (l15 < 2)
                    aw = *(const bf16x8*)(w2_bf + ((dy * 5 + dx) * 2 + l15) * 64 +
                                          c * 32 + l4 * 8);
                else
                    aw = (bf16x8){0, 0, 0, 0, 0, 0, 0, 0};
                bf16x8 bx[4];
#pragma unroll
                for (int n = 0; n < 4; n++) {
                    int px = n * 16 + l15 + dx;
                    int slot4 = l4 ^ (px & 3);
                    bx[n] = *(const bf16x8*)&s_in[((syrel + dy) * 80 + px) * 32 + slot4 * 8];
                }
#pragma unroll
                for (int n = 0; n < 4; n++)
                    acc[n] = __builtin_amdgcn_mfma_f32_16x16x32_bf16(
                        aw, bx[n], acc[n], 0, 0, 0);
            }
        }
    }

    if (l4 == 0 && oy < 130) {
        float bias0 = b2[0], bias1 = b2[1];
#pragma unroll
        for (int n = 0; n < 4; n++) {
            int ox = x0 + n * 16 + l15;
            if (ox < 252) {
                float v0 = acc[n][0] + bias0;
                float v1 = acc[n][1] + bias1;
                size_t o = (size_t)b * 65520 + (size_t)oy * 252 + ox;
                dmap_raw2[o] = 1.f / (1.f + expf(-v0));
                dmap_raw2[o + 32760] = 1.f / (1.f + expf(-v1));
            }
        }
    }
}

// ---------------------------------------------------------------------------
// k_dmap: fused nearest(cols)+mask -> bilinear 130->128 -> bilinear 128->130
// -> out_dmap + normalize/cumsum -> grid. ch0=h->y(grid+1), ch1=w->x(grid+0).
// ---------------------------------------------------------------------------
__global__ __launch_bounds__(256) void k_dmap(const float* __restrict__ dmap_raw2,
                                              float* __restrict__ out_dmap,
                                              float* __restrict__ grid) {
    __shared__ float sA[16900];   // 130x130
    __shared__ float sB[16384];   // 128x128
    const int ch = blockIdx.x, b = blockIdx.y;
    const int tid = threadIdx.x;
    const float SC = (float)(252.0 / 130.0);

    const float* src = dmap_raw2 + (size_t)b * 65520 + (size_t)ch * 32760;
    for (int i = tid; i < 16900; i += 256) {
        int oy = i / 130, ox = i - oy * 130;
        int sx = (int)floorf((float)ox * SC);
        float m = (oy >= 1 && oy <= 128 && ox >= 1 && ox <= 128) ? 2.0f : 0.0f;
        sA[i] = src[oy * 252 + sx] + 0.0009f + m;
    }
    __syncthreads();

    {   // bilinear 130 -> 128
        const float sc = (float)(130.0 / 128.0);
        for (int i = tid; i < 16384; i += 256) {
            int oy = i >> 7, ox = i & 127;
            float sy = ((float)oy + 0.5f) * sc - 0.5f;
            float sx = ((float)ox + 0.5f) * sc - 0.5f;
            float y0f = floorf(sy), x0f = floorf(sx);
            float wy = sy - y0f, wx = sx - x0f;
            int y0 = max(min((int)y0f, 129), 0), y1 = max(min((int)y0f + 1, 129), 0);
            int x0 = max(min((int)x0f, 129), 0), x1 = max(min((int)x0f + 1, 129), 0);
            float top = sA[y0 * 130 + x0] * (1.f - wx) + sA[y0 * 130 + x1] * wx;
            float bot = sA[y1 * 130 + x0] * (1.f - wx) + sA[y1 * 130 + x1] * wx;
            sB[i] = top * (1.f - wy) + bot * wy;
        }
    }
    __syncthreads();

    {   // bilinear 128 -> 130, write out_dmap, stash in sA
        const float sc = (float)(128.0 / 130.0);
        float* od = out_dmap + ((size_t)b * 2 + ch) * 16900;
        for (int i = tid; i < 16900; i += 256) {
            int oy = i / 130, ox = i - oy * 130;
            float sy = ((float)oy + 0.5f) * sc - 0.5f;
            float sx = ((float)ox + 0.5f) * sc - 0.5f;
            float y0f = floorf(sy), x0f = floorf(sx);
            float wy = sy - y0f, wx = sx - x0f;
            int y0 = max(min((int)y0f, 127), 0), y1 = max(min((int)y0f + 1, 127), 0);
            int x0 = max(min((int)x0f, 127), 0), x1 = max(min((int)x0f + 1, 127), 0);
            float top = sB[y0 * 128 + x0] * (1.f - wx) + sB[y0 * 128 + x1] * wx;
            float bot = sB[y1 * 128 + x0] * (1.f - wx) + sB[y1 * 128 + x1] * wx;
            float v = top * (1.f - wy) + bot * wy;
            od[i] = v;
            sA[i] = v;
        }
    }
    __syncthreads();

    if (tid < 130) {
        float* g = grid + (size_t)b * 32768;
        if (ch == 0) {          // ch0 = h -> cumsum down rows -> y (grid+1)
            float s = 0.f;
            for (int r = 0; r < 130; r++) s += sA[r * 130 + tid];
            float inv = 1.f / s;
            float cs = 0.f;
            for (int r = 0; r < 130; r++) {
                cs += sA[r * 130 + tid] * inv;
                if (r >= 1 && r <= 128 && tid >= 1 && tid <= 128)
                    g[((r - 1) * 128 + (tid - 1)) * 2 + 1] = cs * 2.f - 1.f;
            }
        } else {                // ch1 = w -> cumsum across cols -> x (grid+0)
            const float* row = sA + tid * 130;
            float s = 0.f;
            for (int x = 0; x < 130; x++) s += row[x];
            float inv = 1.f / s;
            float cs = 0.f;
            for (int x = 0; x < 130; x++) {
                cs += row[x] * inv;
                if (x >= 1 && x <= 128 && tid >= 1 && tid <= 128)
                    g[((tid - 1) * 128 + (x - 1)) * 2 + 0] = cs * 2.f - 1.f;
            }
        }
    }
}

// ---------------------------------------------------------------------------
// k_sample: grid_sample_bilinear(feat, grid) -> dst (nb,64,128,128) f32.
// XCD-swizzled.
// ---------------------------------------------------------------------------
__global__ __launch_bounds__(256) void k_sample(const float* __restrict__ feat_c,
                                                const float* __restrict__ grid,
                                                float* __restrict__ dst_c) {
    const int lid = blockIdx.x + (blockIdx.y << 3) + (blockIdx.z << 6);
    const int nid = xcd_remap(lid, (int)gridDim.z << 6);
    const int b = nid >> 6;
    const int x = ((nid & 7) << 4) + (threadIdx.x & 15);
    const int y = (((nid >> 3) & 7) << 4) + (threadIdx.x >> 4);

    const float* g = grid + (((size_t)b * 128 + y) * 128 + x) * 2;
    float gx = g[0], gy = g[1];
    float ix = (gx + 1.f) * 128.f - 0.5f;
    float iy = (gy + 1.f) * 128.f - 0.5f;
    float x0f = floorf(ix), y0f = floorf(iy);
    float wx = ix - x0f, wy = iy - y0f;
    int ix0 = (int)x0f, iy0 = (int)y0f;
    int ix1 = ix0 + 1, iy1 = iy0 + 1;
    float vx0 = ((unsigned)ix0 < 256u) ? 1.f : 0.f;
    float vx1 = ((unsigned)ix1 < 256u) ? 1.f : 0.f;
    float vy0 = ((unsigned)iy0 < 256u) ? 1.f : 0.f;
    float vy1 = ((unsigned)iy1 < 256u) ? 1.f : 0.f;
    int cx0 = max(min(ix0, 255), 0), cx1 = max(min(ix1, 255), 0);
    int cy0 = max(min(iy0, 255), 0), cy1 = max(min(iy1, 255), 0);
    float w00 = (1.f - wx) * (1.f - wy) * vx0 * vy0;
    float w01 = wx * (1.f - wy) * vx1 * vy0;
    float w10 = (1.f - wx) * wy * vx0 * vy1;
    float w11 = wx * wy * vx1 * vy1;

    const float* fb = feat_c + (size_t)b * 64 * 65536;
    int o00 = cy0 * 256 + cx0, o01 = cy0 * 256 + cx1;
    int o10 = cy1 * 256 + cx0, o11 = cy1 * 256 + cx1;
    float* d = dst_c + (size_t)b * 64 * 16384 + (size_t)y * 128 + x;
#pragma unroll 4
    for (int c = 0; c < 64; c++) {
        const float* fc = fb + (size_t)c * 65536;
        d[(size_t)c * 16384] = fc[o00] * w00 + fc[o01] * w01 +
                               fc[o10] * w10 + fc[o11] * w11;
    }
}

// ---------------------------------------------------------------------------
static inline size_t align256(size_t x) { return (x + 255) & ~(size_t)255; }

extern "C" void kernel_launch(void* const* d_in, const int* in_sizes, int n_in,
                              void* d_out, int out_size, void* d_ws, size_t ws_size,
                              hipStream_t stream) {
    const float* feat  = (const float*)d_in[0];
    const float* w1    = (const float*)d_in[1];
    const float* b1    = (const float*)d_in[2];
    const float* gamma = (const float*)d_in[3];
    const float* beta  = (const float*)d_in[4];
    const float* rmean = (const float*)d_in[5];
    const float* rvar  = (const float*)d_in[6];
    const float* w2    = (const float*)d_in[7];
    const float* b2    = (const float*)d_in[8];

    float* out = (float*)d_out;                 // reference outputs are f32
    float* out_dst  = out;                      // (16,64,128,128)
    float* out_dmap = out + 16777216;           // (16,2,130,130)

    // pick images-per-chunk nb adaptively from ws_size (deterministic)
    int nb = 1;
    const int cands[5] = {16, 8, 4, 2, 1};
    for (int k = 0; k < 5; ++k) {
        int n = cands[k];
        size_t need = align256((size_t)n * FT_IMG * 2)     // featT bf16 padded
                    + align256((size_t)n * XN_IMG * 2)     // xn bf16 pixel-major
                    + align256(73728)                      // w_bf
                    + align256(12800)                      // w2_bf
                    + align256((size_t)n * 65520 * 4)      // dmap_raw2
                    + align256((size_t)n * 131072);        // grid
        if (need <= ws_size) { nb = n; break; }
    }

    char* p = (char*)d_ws;
    ushort* featT    = (ushort*)p; p += align256((size_t)nb * FT_IMG * 2);
    ushort* xn       = (ushort*)p; p += align256((size_t)nb * XN_IMG * 2);
    ushort* w_bf     = (ushort*)p; p += align256(73728);
    ushort* w2_bf    = (ushort*)p; p += align256(12800);
    float* dmap_raw2 = (float*)p;  p += align256((size_t)nb * 65520 * 4);
    float* grid      = (float*)p;

    k_prep<<<(40064 + nb * 8320 + 255) / 256, 256, 0, stream>>>(
        w1, w2, w_bf, w2_bf, featT, nb);

    const int nchunks = 16 / nb;
    for (int c = 0; c < nchunks; ++c) {
        const float* feat_c = feat + (size_t)c * nb * 64 * 65536;
        float* dst_c  = out_dst  + (size_t)c * nb * 64 * 16384;
        float* dmap_c = out_dmap + (size_t)c * nb * 2 * 16900;

        k_tr<<<dim3(4, 256, nb), 256, 0, stream>>>(feat_c, featT);
        k_conv1<<<dim3(4, 64, nb), 256, 0, stream>>>(featT, w_bf, b1, gamma,
                                                     beta, rmean, rvar, xn);
        k_conv2<<<dim3(4, 33, nb), 256, 0, stream>>>(xn, w2_bf, b2, dmap_raw2);
        k_dmap<<<dim3(2, nb), 256, 0, stream>>>(dmap_raw2, dmap_c, grid);
        k_sample<<<dim3(8, 8, nb), 256, 0, stream>>>(feat_c, grid, dst_c);
    }
}

// Round 17
// 398.528 us; speedup vs baseline: 1.1427x; 1.0016x over previous
//
#include <hip/hip_runtime.h>
#include <hip/hip_bf16.h>

typedef __hip_bfloat16 bf16;
typedef __attribute__((ext_vector_type(8))) short bf16x8;
typedef __attribute__((ext_vector_type(4))) float f32x4;

static __device__ __forceinline__ ushort f2bf(float f) {
    uint u = __float_as_uint(f);
    u += 0x7fff + ((u >> 16) & 1);   // RNE
    return (ushort)(u >> 16);
}

static __device__ __forceinline__ void gl_lds16(const void* g, void* l) {
    __builtin_amdgcn_global_load_lds(
        (const __attribute__((address_space(1))) uint*)g,
        (__attribute__((address_space(3))) uint*)l, 16, 0, 0);
}

// bijective XCD remap (m204): orig -> nid, any total count
static __device__ __forceinline__ int xcd_remap(int lid, int nwg) {
    int q = nwg >> 3, r = nwg & 7;
    int xcd = lid & 7, idx = lid >> 3;
    return (xcd < r ? xcd * (q + 1) : r * (q + 1) + (xcd - r) * q) + idx;
}

// featT geometry: padded pixel-major bf16, [yp(258)][xp(264)][64 ic slots]
// value of (y,x,ic) at yp=y+1, xp=x+1, octet slot (ic>>3) ^ (xp&7), elem ic&7.
#define FT_ROW 264
#define FT_IMG ((size_t)258 * 264 * 64)
// xn geometry: pixel-major bf16 [y(256)][x(256)][64 oc slots], octet ^ (x&7).
#define XN_IMG ((size_t)256 * 256 * 64)

// ---------------------------------------------------------------------------
// k_prep: w1 -> w_bf[tap][oc][ic ^ ((oc&7)<<3)] bf16 (SWIZZLED, for LDS-staged
// conv1); w2 -> w2_bf[tap(25)][oc(2)][ic(64)]; zero featT 1-px border.
// ---------------------------------------------------------------------------
__global__ __launch_bounds__(256) void k_prep(const float* __restrict__ w1,
                                              const float* __restrict__ w2,
                                              ushort* __restrict__ w_bf,
                                              ushort* __restrict__ w2_bf,
                                              ushort* __restrict__ featT, int nb) {
    int i = blockIdx.x * 256 + threadIdx.x;
    if (i < 36864) {                       // w1: i = ((oc*64+ic)*3+dy)*3+dx
        int oc = i / 576, rem = i - oc * 576;
        int ic = rem / 9, tap = rem - ic * 9;
        w_bf[tap * 4096 + oc * 64 + (ic ^ ((oc & 7) << 3))] = f2bf(w1[i]);
    } else if (i < 40064) {                // w2: j = (oc*64+ic)*25 + tap
        int j = i - 36864;
        int oc = j / 1600, rem = j - oc * 1600;
        int ic = rem / 25, tap = rem - ic * 25;
        w2_bf[(tap * 2 + oc) * 64 + ic] = f2bf(w2[j]);
    } else {                               // featT border zero
        int t = i - 40064;
        const int per = 1040 * 8;
        if (t >= nb * per) return;
        int b = t / per, u = t - b * per;
        int px = u >> 3, oct = u & 7;
        int yp, xp;
        if (px < 264)       { yp = 0;   xp = px; }
        else if (px < 528)  { yp = 257; xp = px - 264; }
        else { int k = px - 528; yp = 1 + (k >> 1); xp = (k & 1) ? 257 : 0; }
        ushort* p = featT + (size_t)b * FT_IMG + ((size_t)yp * FT_ROW + xp) * 64 + oct * 8;
        *(uint4*)p = make_uint4(0u, 0u, 0u, 0u);
    }
}

// ---------------------------------------------------------------------------
// k_tr: feat (nb,64,256,256) f32 -> featT bf16 pixel-major, swizzled.
// ---------------------------------------------------------------------------
__global__ __launch_bounds__(256) void k_tr(const float* __restrict__ feat_c,
                                            ushort* __restrict__ featT) {
    __shared__ ushort s_t[64][72];       // [ic][x], padded
    const int b = blockIdx.z, y = blockIdx.y, x0 = blockIdx.x * 64;
    const int t = threadIdx.x;
    const int xl = t & 63, icg = t >> 6;

    const float* fb = feat_c + (size_t)b * 64 * 65536 + (size_t)y * 256 + x0 + xl;
#pragma unroll
    for (int k = 0; k < 16; ++k) {
        int ic = icg * 16 + k;
        s_t[ic][xl] = f2bf(fb[(size_t)ic * 65536]);
    }
    __syncthreads();

    ushort* ob = featT + (size_t)b * FT_IMG + ((size_t)(y + 1) * FT_ROW + (x0 + 1)) * 64;
#pragma unroll
    for (int u2 = 0; u2 < 2; ++u2) {
        int u = u2 * 256 + t;            // 512 units: (x, octet)
        int x = u >> 3, oct = u & 7;
        int xp7 = (x + 1) & 7;           // (xp&7), since x0 % 64 == 0
        uint p0 = (uint)s_t[oct * 8 + 0][x] | ((uint)s_t[oct * 8 + 1][x] << 16);
        uint p1 = (uint)s_t[oct * 8 + 2][x] | ((uint)s_t[oct * 8 + 3][x] << 16);
        uint p2 = (uint)s_t[oct * 8 + 4][x] | ((uint)s_t[oct * 8 + 5][x] << 16);
        uint p3 = (uint)s_t[oct * 8 + 6][x] | ((uint)s_t[oct * 8 + 7][x] << 16);
        *(uint4*)(ob + (size_t)x * 64 + (oct ^ xp7) * 8) = make_uint4(p0, p1, p2, p3);
    }
}

// ---------------------------------------------------------------------------
// k_conv1 (MFMA + DMA staging, r13 form + T5 setprio): 3x3 conv + bias + BN +
// ReLU6 + L2-norm. LDS-staged weights (per-dy), 2 blocks/CU.
// ---------------------------------------------------------------------------
__global__ __launch_bounds__(256, 2) void k_conv1(
    const ushort* __restrict__ featT, const ushort* __restrict__ w_bf,
    const float* __restrict__ b1, const float* __restrict__ gamma,
    const float* __restrict__ beta, const float* __restrict__ rmean,
    const float* __restrict__ rvar, ushort* __restrict__ xn) {
    __shared__ __align__(16) ushort s_in[6 * 72 * 64];   // 55296 B
    __shared__ __align__(16) ushort s_w[12288];          // 24576 B
    __shared__ float2 s_bn[64];

    const int lid = blockIdx.x + (blockIdx.y << 2) + (blockIdx.z << 8);
    const int nid = xcd_remap(lid, (int)gridDim.z << 8);
    const int b   = nid >> 8;
    const int x0p = (nid & 3) * 64;
    const int y0  = ((nid >> 2) & 63) * 4;

    const int tid = threadIdx.x;
    const int lane = tid & 63;
    const int w    = tid >> 6;
    const int l15  = lane & 15;
    const int l4   = lane >> 4;

    if (tid < 64) {
        float inv = 1.0f / sqrtf(rvar[tid] + 1e-5f);
        float sA = inv * gamma[tid];
        float sB = (b1[tid] - rmean[tid]) * sA + beta[tid];
        s_bn[tid] = make_float2(sA, sB);
    }

    const ushort* fT = featT + (size_t)b * FT_IMG;
    {
        int aStart = w * 13 + (w < 2 ? w : 2);       // {0,14,28,41}
        int aCnt   = (w < 2) ? 14 : 13;
        for (int q = 0; q < aCnt; ++q) {
            int o = (aStart + q) * 1024;
            int r = o / 9216;
            int rem = o - r * 9216;
            const ushort* g = fT + ((size_t)(y0 + r) * FT_ROW + x0p) * 64 +
                              (rem >> 1) + lane * 8;
            gl_lds16(g, (char*)s_in + o);
        }
    }

    f32x4 acc[4][4];
#pragma unroll
    for (int m = 0; m < 4; m++)
#pragma unroll
        for (int n = 0; n < 4; n++) acc[m][n] = (f32x4){0.f, 0.f, 0.f, 0.f};

    for (int dy = 0; dy < 3; dy++) {
        __syncthreads();
        {
            for (int q = 0; q < 6; ++q) {
                int o = (w * 6 + q) * 1024;
                const ushort* g = w_bf + dy * 12288 + (o >> 1) + lane * 8;
                gl_lds16(g, (char*)s_w + o);
            }
        }
        __syncthreads();
        __builtin_amdgcn_s_setprio(1);   // T5: favor compute waves vs staging
#pragma unroll
        for (int dx = 0; dx < 3; dx++) {
#pragma unroll
            for (int ks = 0; ks < 2; ks++) {
                bf16x8 a[4], bb[4];
#pragma unroll
                for (int m = 0; m < 4; m++) {
                    int c = m * 16 + l15 + dx;
                    int slot = (ks * 4 + l4) ^ (c & 7);
                    a[m] = *(const bf16x8*)&s_in[((w + dy) * 72 + c) * 64 + slot * 8];
                }
#pragma unroll
                for (int n = 0; n < 4; n++) {
                    int oc = n * 16 + l15;
                    int slot = (ks * 4 + l4) ^ (oc & 7);
                    bb[n] = *(const bf16x8*)&s_w[(dx * 64 + oc) * 64 + slot * 8];
                }
#pragma unroll
                for (int m = 0; m < 4; m++)
#pragma unroll
                    for (int n = 0; n < 4; n++)   // C[oc row, px col]
                        acc[m][n] = __builtin_amdgcn_mfma_f32_16x16x32_bf16(
                            bb[n], a[m], acc[m][n], 0, 0, 0);
            }
        }
        __builtin_amdgcn_s_setprio(0);
    }

    float sA[4][4], sB[4][4];
#pragma unroll
    for (int n = 0; n < 4; n++)
#pragma unroll
        for (int j = 0; j < 4; j++) {
            float2 t = s_bn[n * 16 + l4 * 4 + j];
            sA[n][j] = t.x; sB[n][j] = t.y;
        }
    const int y = y0 + w;
    ushort* xb = xn + (size_t)b * XN_IMG;

#pragma unroll
    for (int m = 0; m < 4; m++) {
        float vv[4][4];
        float ss = 0.f;
#pragma unroll
        for (int n = 0; n < 4; n++)
#pragma unroll
            for (int j = 0; j < 4; j++) {
                float v = fmaf(acc[m][n][j], sA[n][j], sB[n][j]);
                v = fminf(fmaxf(v, 0.f), 6.f);
                vv[n][j] = v;
                ss = fmaf(v, v, ss);
            }
        ss += __shfl_xor(ss, 16);
        ss += __shfl_xor(ss, 32);
        float nrm = sqrtf(ss);
        float sc = (nrm > 0.09f) ? (1.0f / (nrm + 9e-8f)) : 0.f;

        int x = x0p + m * 16 + l15;
        ushort* pb = xb + ((size_t)y * 256 + x) * 64;
        int so = (l4 & 1) * 4;
#pragma unroll
        for (int n = 0; n < 4; n++) {
            int oct = n * 2 + (l4 >> 1);
            int slot = oct ^ (x & 7);
            uint2 pk;
            pk.x = (uint)f2bf(vv[n][0] * sc) | ((uint)f2bf(vv[n][1] * sc) << 16);
            pk.y = (uint)f2bf(vv[n][2] * sc) | ((uint)f2bf(vv[n][3] * sc) << 16);
            *(uint2*)(pb + slot * 8 + so) = pk;
        }
    }
}

// ---------------------------------------------------------------------------
// k_conv2 (MFMA, ROW-SAMPLED, + T5 setprio): 5x5 conv + sigmoid at the 130
// sampled rows.
// ---------------------------------------------------------------------------
__global__ __launch_bounds__(256, 2) void k_conv2(
    const ushort* __restrict__ xn, const ushort* __restrict__ w2_bf,
    const float* __restrict__ b2, float* __restrict__ dmap_raw2) {
    __shared__ __align__(16) ushort s_in[11 * 80 * 32];   // 56320 B

    // grid (4, 33, nb), XCD-swizzled
    const int lid = blockIdx.x + (blockIdx.y << 2) + blockIdx.z * 132;
    const int nid = xcd_remap(lid, (int)gridDim.z * 132);
    const int b   = nid / 132;
    const int rem = nid - b * 132;
    const int x0  = (rem & 3) * 64;
    const int oy0 = (rem >> 2) * 4;

    const int tid = threadIdx.x;
    const int lane = tid & 63;
    const int w    = tid >> 6;
    const int l15  = lane & 15;
    const int l4   = lane >> 4;

    const float SC = (float)(252.0 / 130.0);
    const int syb = (int)floorf((float)oy0 * SC);
    const int oy  = oy0 + w;
    const int syrel = (int)floorf((float)oy * SC) - syb;   // 0..6

    const ushort* xb = xn + (size_t)b * XN_IMG;

    f32x4 acc[4];
#pragma unroll
    for (int n = 0; n < 4; n++) acc[n] = (f32x4){0.f, 0.f, 0.f, 0.f};

    for (int c = 0; c < 2; ++c) {
        if (c) __syncthreads();            // chunk-0 reads complete
        {
            int st  = (w < 3) ? w * 14 : 42;
            int cnt = (w < 3) ? 14 : 13;
            for (int q = 0; q < cnt; ++q) {
                int i = st + q;
                int r = i / 5;
                int px0 = (i - r * 5) * 16;
                int gr = min(syb + r, 255);
                int px = px0 + (lane >> 2);
                int gx = x0 + px;
                const ushort* g = xb + (size_t)(gr * 256 + gx) * 64 +
                                  ((((gx >> 2) & 1) ^ c) * 32) + (lane & 3) * 8;
                gl_lds16(g, (char*)s_in + i * 1024);
            }
        }
        __syncthreads();

        __builtin_amdgcn_s_setprio(1);   // T5
#pragma unroll
        for (int dy = 0; dy < 5; dy++) {
#pragma unroll
            for (int dx = 0; dx < 5; dx++) {
                bf16x8 aw;
                if (l15 < 2)
                    aw = *(const bf16x8*)(w2_bf + ((dy * 5 + dx) * 2 + l15) * 64 +
                                          c * 32 + l4 * 8);
                else
                    aw = (bf16x8){0, 0, 0, 0, 0, 0, 0, 0};
                bf16x8 bx[4];
#pragma unroll
                for (int n = 0; n < 4; n++) {
                    int px = n * 16 + l15 + dx;
                    int slot4 = l4 ^ (px & 3);
                    bx[n] = *(const bf16x8*)&s_in[((syrel + dy) * 80 + px) * 32 + slot4 * 8];
                }
#pragma unroll
                for (int n = 0; n < 4; n++)
                    acc[n] = __builtin_amdgcn_mfma_f32_16x16x32_bf16(
                        aw, bx[n], acc[n], 0, 0, 0);
            }
        }
        __builtin_amdgcn_s_setprio(0);
    }

    if (l4 == 0 && oy < 130) {
        float bias0 = b2[0], bias1 = b2[1];
#pragma unroll
        for (int n = 0; n < 4; n++) {
            int ox = x0 + n * 16 + l15;
            if (ox < 252) {
                float v0 = acc[n][0] + bias0;
                float v1 = acc[n][1] + bias1;
                size_t o = (size_t)b * 65520 + (size_t)oy * 252 + ox;
                dmap_raw2[o] = 1.f / (1.f + expf(-v0));
                dmap_raw2[o + 32760] = 1.f / (1.f + expf(-v1));
            }
        }
    }
}

// ---------------------------------------------------------------------------
// k_dmap: fused nearest(cols)+mask -> bilinear 130->128 -> bilinear 128->130
// -> out_dmap + normalize/cumsum -> grid. ch0=h->y(grid+1), ch1=w->x(grid+0).
// ---------------------------------------------------------------------------
__global__ __launch_bounds__(256) void k_dmap(const float* __restrict__ dmap_raw2,
                                              float* __restrict__ out_dmap,
                                              float* __restrict__ grid) {
    __shared__ float sA[16900];   // 130x130
    __shared__ float sB[16384];   // 128x128
    const int ch = blockIdx.x, b = blockIdx.y;
    const int tid = threadIdx.x;
    const float SC = (float)(252.0 / 130.0);

    const float* src = dmap_raw2 + (size_t)b * 65520 + (size_t)ch * 32760;
    for (int i = tid; i < 16900; i += 256) {
        int oy = i / 130, ox = i - oy * 130;
        int sx = (int)floorf((float)ox * SC);
        float m = (oy >= 1 && oy <= 128 && ox >= 1 && ox <= 128) ? 2.0f : 0.0f;
        sA[i] = src[oy * 252 + sx] + 0.0009f + m;
    }
    __syncthreads();

    {   // bilinear 130 -> 128
        const float sc = (float)(130.0 / 128.0);
        for (int i = tid; i < 16384; i += 256) {
            int oy = i >> 7, ox = i & 127;
            float sy = ((float)oy + 0.5f) * sc - 0.5f;
            float sx = ((float)ox + 0.5f) * sc - 0.5f;
            float y0f = floorf(sy), x0f = floorf(sx);
            float wy = sy - y0f, wx = sx - x0f;
            int y0 = max(min((int)y0f, 129), 0), y1 = max(min((int)y0f + 1, 129), 0);
            int x0 = max(min((int)x0f, 129), 0), x1 = max(min((int)x0f + 1, 129), 0);
            float top = sA[y0 * 130 + x0] * (1.f - wx) + sA[y0 * 130 + x1] * wx;
            float bot = sA[y1 * 130 + x0] * (1.f - wx) + sA[y1 * 130 + x1] * wx;
            sB[i] = top * (1.f - wy) + bot * wy;
        }
    }
    __syncthreads();

    {   // bilinear 128 -> 130, write out_dmap, stash in sA
        const float sc = (float)(128.0 / 130.0);
        float* od = out_dmap + ((size_t)b * 2 + ch) * 16900;
        for (int i = tid; i < 16900; i += 256) {
            int oy = i / 130, ox = i - oy * 130;
            float sy = ((float)oy + 0.5f) * sc - 0.5f;
            float sx = ((float)ox + 0.5f) * sc - 0.5f;
            float y0f = floorf(sy), x0f = floorf(sx);
            float wy = sy - y0f, wx = sx - x0f;
            int y0 = max(min((int)y0f, 127), 0), y1 = max(min((int)y0f + 1, 127), 0);
            int x0 = max(min((int)x0f, 127), 0), x1 = max(min((int)x0f + 1, 127), 0);
            float top = sB[y0 * 128 + x0] * (1.f - wx) + sB[y0 * 128 + x1] * wx;
            float bot = sB[y1 * 128 + x0] * (1.f - wx) + sB[y1 * 128 + x1] * wx;
            float v = top * (1.f - wy) + bot * wy;
            od[i] = v;
            sA[i] = v;
        }
    }
    __syncthreads();

    if (tid < 130) {
        float* g = grid + (size_t)b * 32768;
        if (ch == 0) {          // ch0 = h -> cumsum down rows -> y (grid+1)
            float s = 0.f;
            for (int r = 0; r < 130; r++) s += sA[r * 130 + tid];
            float inv = 1.f / s;
            float cs = 0.f;
            for (int r = 0; r < 130; r++) {
                cs += sA[r * 130 + tid] * inv;
                if (r >= 1 && r <= 128 && tid >= 1 && tid <= 128)
                    g[((r - 1) * 128 + (tid - 1)) * 2 + 1] = cs * 2.f - 1.f;
            }
        } else {                // ch1 = w -> cumsum across cols -> x (grid+0)
            const float* row = sA + tid * 130;
            float s = 0.f;
            for (int x = 0; x < 130; x++) s += row[x];
            float inv = 1.f / s;
            float cs = 0.f;
            for (int x = 0; x < 130; x++) {
                cs += row[x] * inv;
                if (x >= 1 && x <= 128 && tid >= 1 && tid <= 128)
                    g[((tid - 1) * 128 + (x - 1)) * 2 + 0] = cs * 2.f - 1.f;
            }
        }
    }
}

// ---------------------------------------------------------------------------
// k_sample: grid_sample_bilinear(feat, grid) -> dst (nb,64,128,128) f32.
// XCD-swizzled.
// ---------------------------------------------------------------------------
__global__ __launch_bounds__(256) void k_sample(const float* __restrict__ feat_c,
                                                const float* __restrict__ grid,
                                                float* __restrict__ dst_c) {
    const int lid = blockIdx.x + (blockIdx.y << 3) + (blockIdx.z << 6);
    const int nid = xcd_remap(lid, (int)gridDim.z << 6);
    const int b = nid >> 6;
    const int x = ((nid & 7) << 4) + (threadIdx.x & 15);
    const int y = (((nid >> 3) & 7) << 4) + (threadIdx.x >> 4);

    const float* g = grid + (((size_t)b * 128 + y) * 128 + x) * 2;
    float gx = g[0], gy = g[1];
    float ix = (gx + 1.f) * 128.f - 0.5f;
    float iy = (gy + 1.f) * 128.f - 0.5f;
    float x0f = floorf(ix), y0f = floorf(iy);
    float wx = ix - x0f, wy = iy - y0f;
    int ix0 = (int)x0f, iy0 = (int)y0f;
    int ix1 = ix0 + 1, iy1 = iy0 + 1;
    float vx0 = ((unsigned)ix0 < 256u) ? 1.f : 0.f;
    float vx1 = ((unsigned)ix1 < 256u) ? 1.f : 0.f;
    float vy0 = ((unsigned)iy0 < 256u) ? 1.f : 0.f;
    float vy1 = ((unsigned)iy1 < 256u) ? 1.f : 0.f;
    int cx0 = max(min(ix0, 255), 0), cx1 = max(min(ix1, 255), 0);
    int cy0 = max(min(iy0, 255), 0), cy1 = max(min(iy1, 255), 0);
    float w00 = (1.f - wx) * (1.f - wy) * vx0 * vy0;
    float w01 = wx * (1.f - wy) * vx1 * vy0;
    float w10 = (1.f - wx) * wy * vx0 * vy1;
    float w11 = wx * wy * vx1 * vy1;

    const float* fb = feat_c + (size_t)b * 64 * 65536;
    int o00 = cy0 * 256 + cx0, o01 = cy0 * 256 + cx1;
    int o10 = cy1 * 256 + cx0, o11 = cy1 * 256 + cx1;
    float* d = dst_c + (size_t)b * 64 * 16384 + (size_t)y * 128 + x;
#pragma unroll 4
    for (int c = 0; c < 64; c++) {
        const float* fc = fb + (size_t)c * 65536;
        d[(size_t)c * 16384] = fc[o00] * w00 + fc[o01] * w01 +
                               fc[o10] * w10 + fc[o11] * w11;
    }
}

// ---------------------------------------------------------------------------
static inline size_t align256(size_t x) { return (x + 255) & ~(size_t)255; }

extern "C" void kernel_launch(void* const* d_in, const int* in_sizes, int n_in,
                              void* d_out, int out_size, void* d_ws, size_t ws_size,
                              hipStream_t stream) {
    const float* feat  = (const float*)d_in[0];
    const float* w1    = (const float*)d_in[1];
    const float* b1    = (const float*)d_in[2];
    const float* gamma = (const float*)d_in[3];
    const float* beta  = (const float*)d_in[4];
    const float* rmean = (const float*)d_in[5];
    const float* rvar  = (const float*)d_in[6];
    const float* w2    = (const float*)d_in[7];
    const float* b2    = (const float*)d_in[8];

    float* out = (float*)d_out;                 // reference outputs are f32
    float* out_dst  = out;                      // (16,64,128,128)
    float* out_dmap = out + 16777216;           // (16,2,130,130)

    // pick images-per-chunk nb adaptively from ws_size (deterministic)
    int nb = 1;
    const int cands[5] = {16, 8, 4, 2, 1};
    for (int k = 0; k < 5; ++k) {
        int n = cands[k];
        size_t need = align256((size_t)n * FT_IMG * 2)     // featT bf16 padded
                    + align256((size_t)n * XN_IMG * 2)     // xn bf16 pixel-major
                    + align256(73728)                      // w_bf
                    + align256(12800)                      // w2_bf
                    + align256((size_t)n * 65520 * 4)      // dmap_raw2
                    + align256((size_t)n * 131072);        // grid
        if (need <= ws_size) { nb = n; break; }
    }

    char* p = (char*)d_ws;
    ushort* featT    = (ushort*)p; p += align256((size_t)nb * FT_IMG * 2);
    ushort* xn       = (ushort*)p; p += align256((size_t)nb * XN_IMG * 2);
    ushort* w_bf     = (ushort*)p; p += align256(73728);
    ushort* w2_bf    = (ushort*)p; p += align256(12800);
    float* dmap_raw2 = (float*)p;  p += align256((size_t)nb * 65520 * 4);
    float* grid      = (float*)p;

    k_prep<<<(40064 + nb * 8320 + 255) / 256, 256, 0, stream>>>(
        w1, w2, w_bf, w2_bf, featT, nb);

    const int nchunks = 16 / nb;
    for (int c = 0; c < nchunks; ++c) {
        const float* feat_c = feat + (size_t)c * nb * 64 * 65536;
        float* dst_c  = out_dst  + (size_t)c * nb * 64 * 16384;
        float* dmap_c = out_dmap + (size_t)c * nb * 2 * 16900;

        k_tr<<<dim3(4, 256, nb), 256, 0, stream>>>(feat_c, featT);
        k_conv1<<<dim3(4, 64, nb), 256, 0, stream>>>(featT, w_bf, b1, gamma,
                                                     beta, rmean, rvar, xn);
        k_conv2<<<dim3(4, 33, nb), 256, 0, stream>>>(xn, w2_bf, b2, dmap_raw2);
        k_dmap<<<dim3(2, nb), 256, 0, stream>>>(dmap_raw2, dmap_c, grid);
        k_sample<<<dim3(8, 8, nb), 256, 0, stream>>>(feat_c, grid, dst_c);
    }
}